// Round 1
// baseline (464.012 us; speedup 1.0000x reference)
//
#include <hip/hip_runtime.h>

// RPDC depthwise sparse-5x5 (pixel-difference) conv.
// x: (16,256,128,128) fp32, weight: (256,1,3,3) fp32, out same shape as x.
//
// out(h,w) = t0*(A[w-2]-B[w-1]) + t1*(A[w]-B[w]) + t2*(A[w+2]-B[w+1])
//          + t3*(C[w-2]-C[w-1]) + t4*(C[w+2]-C[w+1])
//          + t5*(E[w-2]-D[w-1]) + t6*(E[w]-D[w]) + t7*(E[w+2]-D[w+1])
// where A..E = input rows h-2..h+2 (zero outside), tj = weight[c][1+j] (flat).
//
// Strategy: register sliding window down H. One thread per (plane, column).
// 5 rows x 5 shifted cols live in regs; 5 coalesced loads + 16 VALU + 1 store
// per output. Memory-bound: ~1.07 GB total HBM traffic -> ~170 us floor.

#define HH 128
#define WW 128

__global__ __launch_bounds__(256, 8) void rpdc_kernel(
    const float* __restrict__ x, const float* __restrict__ wt,
    float* __restrict__ out, int C)
{
    const int tid = threadIdx.x;
    const int w = tid & (WW - 1);
    const int plane = blockIdx.x * 2 + (tid >> 7);   // (n*C + c)
    const int c = plane & (C - 1);                   // C = 256 (pow2)

    const float* wp = wt + (size_t)c * 9;
    const float t0 = wp[1], t1 = wp[2], t2 = wp[3], t3 = wp[4],
                t4 = wp[5], t5 = wp[6], t6 = wp[7], t7 = wp[8];

    const float* xp = x + (size_t)plane * (HH * WW);
    float* op = out + (size_t)plane * (HH * WW) + w;

    // clamped column offsets + 0/1 masks (zero-pad semantics, no divergence)
    const int o0 = (w >= 2) ? (w - 2) : 0;
    const int o1 = (w >= 1) ? (w - 1) : 0;
    const int o2 = w;
    const int o3 = (w <= WW - 2) ? (w + 1) : (WW - 1);
    const int o4 = (w <= WW - 3) ? (w + 2) : (WW - 1);
    const float m0 = (w >= 2) ? 1.f : 0.f;
    const float m1 = (w >= 1) ? 1.f : 0.f;
    const float m3 = (w <= WW - 2) ? 1.f : 0.f;
    const float m4 = (w <= WW - 3) ? 1.f : 0.f;

    // sliding rows: a=h-2, b=h-1, cc=h, d=h+1, e=h+2; index k = col (w-2+k)
    float a[5], b[5], cc[5], d[5], e[5];
#pragma unroll
    for (int k = 0; k < 5; ++k) { a[k] = 0.f; b[k] = 0.f; }

    {   // prologue: rows 0,1,2 -> cc,d,e
        const float* p = xp;
        cc[0] = p[o0] * m0; cc[1] = p[o1] * m1; cc[2] = p[o2];
        cc[3] = p[o3] * m3; cc[4] = p[o4] * m4;
        p += WW;
        d[0] = p[o0] * m0; d[1] = p[o1] * m1; d[2] = p[o2];
        d[3] = p[o3] * m3; d[4] = p[o4] * m4;
        p += WW;
        e[0] = p[o0] * m0; e[1] = p[o1] * m1; e[2] = p[o2];
        e[3] = p[o3] * m3; e[4] = p[o4] * m4;
    }

    const float* pn = xp + 3 * WW;   // next row to load (h+3)
#pragma unroll 4
    for (int h = 0; h < HH; ++h) {
        float r = t0 * (a[0] - b[1]);
        r += t1 * (a[2] - b[2]);
        r += t2 * (a[4] - b[3]);
        r += t3 * (cc[0] - cc[1]);
        r += t4 * (cc[4] - cc[3]);
        r += t5 * (e[0] - d[1]);
        r += t6 * (e[2] - d[2]);
        r += t7 * (e[4] - d[3]);
        op[h * WW] = r;

#pragma unroll
        for (int k = 0; k < 5; ++k) { a[k] = b[k]; b[k] = cc[k]; cc[k] = d[k]; d[k] = e[k]; }

        if (h + 3 < HH) {            // wave-uniform branch
            e[0] = pn[o0] * m0; e[1] = pn[o1] * m1; e[2] = pn[o2];
            e[3] = pn[o3] * m3; e[4] = pn[o4] * m4;
            pn += WW;
        } else {
#pragma unroll
            for (int k = 0; k < 5; ++k) e[k] = 0.f;
        }
    }
}

extern "C" void kernel_launch(void* const* d_in, const int* in_sizes, int n_in,
                              void* d_out, int out_size, void* d_ws, size_t ws_size,
                              hipStream_t stream) {
    const float* x = (const float*)d_in[0];
    const float* wt = (const float*)d_in[1];
    float* out = (float*)d_out;

    const int C = in_sizes[1] / 9;                 // 256
    const int planes = in_sizes[0] / (HH * WW);    // N*C = 4096

    dim3 grid(planes / 2);   // 2 planes per 256-thread block
    dim3 block(256);
    rpdc_kernel<<<grid, block, 0, stream>>>(x, wt, out, C);
}